// Round 3
// baseline (673.978 us; speedup 1.0000x reference)
//
#include <hip/hip_runtime.h>

// ---- problem constants ----
#define HWSZ 9216            // 96*96
#define NB   16
#define CIN  256
#define NH   10
#define NP   6
#define NPER 8847360         // NP*NB*NH*HWSZ  (one output tensor)
#define PSTRIDE 1474560      // NB*NH*HWSZ (part stride in xp/xh/out)

// ---- f32 weight workspace layout (element offsets) ----
#define WT_LD     72         // padded row length of transposed big weight [256][72]
#define OFF_WT    0
#define OFF_WATT  18432
#define OFF_BATT  18492
#define OFF_WDPX  18498
#define OFF_BDP   18598
#define OFF_BPROJ 18608
#define OFF_WGATE 18668
#define OFF_BGATE 18788
#define OFF_WUPD  18794
#define OFF_BUPD  20594
#define WS_TOTAL  20654

static __device__ __forceinline__ float sigmoidf_(float x) {
  return 1.0f / (1.0f + __expf(-x));
}

// Gather all f32 weights/biases into d_ws.
// Big matrix stored transposed+padded: Wt[c][o], o<10 -> w_dp_f[o][c], 10<=o<70 -> w_proj[(o-10)][c]
__global__ void prep_weights(const float* __restrict__ w_att,
                             const float* __restrict__ b_att,
                             const float* __restrict__ w_dp_f,
                             const float* __restrict__ w_dp_x,
                             const float* __restrict__ b_dp,
                             const float* __restrict__ w_proj,
                             const float* __restrict__ b_proj,
                             const float* __restrict__ w_gate,
                             const float* __restrict__ b_gate,
                             const float* __restrict__ w_upd,
                             const float* __restrict__ b_upd,
                             float* __restrict__ ws)
{
  int i = blockIdx.x * 256 + threadIdx.x;
  if (i >= WS_TOTAL) return;
  float v;
  if (i < OFF_WATT) {
    int c = i / WT_LD, o = i % WT_LD;
    if (o < 10)       v = w_dp_f[o * CIN + c];
    else if (o < 70)  v = w_proj[(o - 10) * CIN + c];
    else              v = 0.f;
  }
  else if (i < OFF_BATT)  v = w_att [i - OFF_WATT ];
  else if (i < OFF_WDPX)  v = b_att [i - OFF_BATT ];
  else if (i < OFF_BDP)   v = w_dp_x[i - OFF_WDPX ];
  else if (i < OFF_BPROJ) v = b_dp  [i - OFF_BDP  ];
  else if (i < OFF_WGATE) v = b_proj[i - OFF_BPROJ];
  else if (i < OFF_BGATE) v = w_gate[i - OFF_WGATE];
  else if (i < OFF_WUPD)  v = b_gate[i - OFF_BGATE];
  else if (i < OFF_BUPD)  v = w_upd [i - OFF_WUPD ];
  else                    v = b_upd [i - OFF_BUPD ];
  ws[i] = v;
}

// One thread per pixel. grid = 576 (16 images * 36 tiles), block = 256.
__global__ __launch_bounds__(256) void part_graph_main(
    const float* __restrict__ p_fea,
    const float* __restrict__ xp,
    const float* __restrict__ xh,
    const float* __restrict__ ws,
    float* __restrict__ out)
{
  const int b = blockIdx.x / 36;
  const int s = (blockIdx.x % 36) * 256 + threadIdx.x;
  const size_t bofs = (size_t)b * (NH * HWSZ) + s;

  // ---- big matvec: acc[0..9] = g = Wdpf@f ; acc[10+p*10+d] = proj[p][d] (pre-bias) ----
  float acc[70];
#pragma unroll
  for (int o = 0; o < 70; ++o) acc[o] = 0.f;

  const float* f = p_fea + (size_t)b * CIN * HWSZ + s;
  for (int c0 = 0; c0 < CIN; c0 += 4) {
    float fv0 = f[(size_t)(c0 + 0) * HWSZ];
    float fv1 = f[(size_t)(c0 + 1) * HWSZ];
    float fv2 = f[(size_t)(c0 + 2) * HWSZ];
    float fv3 = f[(size_t)(c0 + 3) * HWSZ];
    const float* w0 = ws + OFF_WT + (size_t)(c0 + 0) * WT_LD;  // wave-uniform -> s_load
    const float* w1 = w0 + WT_LD;
    const float* w2 = w1 + WT_LD;
    const float* w3 = w2 + WT_LD;
#pragma unroll
    for (int o = 0; o < 70; ++o) {
      float a = acc[o];
      a = fmaf(w0[o], fv0, a);
      a = fmaf(w1[o], fv1, a);
      a = fmaf(w2[o], fv2, a);
      a = fmaf(w3[o], fv3, a);
      acc[o] = a;
    }
  }

  // ---- att & gate (sigmoids) ----
  float att[6], gate[6];
#pragma unroll
  for (int p = 0; p < 6; ++p) {
    float asum = ws[OFF_BATT + p];
    float gsum = ws[OFF_BGATE + p];
    const int hf = (p >= 4) ? 1 : 0;
#pragma unroll
    for (int ch = 0; ch < 10; ++ch) {
      float x  = xp[(size_t)p  * PSTRIDE + bofs + (size_t)ch * HWSZ];
      float hv = xh[(size_t)hf * PSTRIDE + bofs + (size_t)ch * HWSZ];
      asum = fmaf(ws[OFF_WATT + p * 10 + ch], x, asum);
      gsum = fmaf(ws[OFF_WGATE + p * 20 + 10 + ch], x, gsum);   // xp half of cat
      gsum = fmaf(ws[OFF_WGATE + p * 20 + ch], hv, gsum);       // xh half of cat
    }
    att[p]  = sigmoidf_(asum);
    gate[p] = sigmoidf_(gsum);
  }

  // ---- dp per part; keep dp1 and S1 = sum_{q!=1} att_q * dp_q ----
  float dp1[10], S1[10], sA = 0.f;
#pragma unroll
  for (int ch = 0; ch < 10; ++ch) { S1[ch] = 0.f; dp1[ch] = 0.f; }
#pragma unroll
  for (int q = 0; q < 6; ++q) {
    float xq[10];
#pragma unroll
    for (int ch = 0; ch < 10; ++ch)
      xq[ch] = xp[(size_t)q * PSTRIDE + bofs + (size_t)ch * HWSZ];
#pragma unroll
    for (int ch = 0; ch < 10; ++ch) {
      float t = acc[ch] + ws[OFF_BDP + ch];
#pragma unroll
      for (int j = 0; j < 10; ++j)
        t = fmaf(ws[OFF_WDPX + ch * 10 + j], xq[j], t);
      t = fmaxf(t, 0.f);                  // relu -> dp_q[ch]
      if (q == 1) dp1[ch] = t;
      else        S1[ch] = fmaf(att[q], t, S1[ch]);
    }
    if (q != 1) sA += att[q];
  }

  // ---- per-part epilogue: xpp, xhp, update; store 3 outputs ----
#pragma unroll
  for (int p = 0; p < 6; ++p) {
    float xpv[10], xppv[10], xhpv[10];
#pragma unroll
    for (int ch = 0; ch < 10; ++ch)
      xpv[ch] = xp[(size_t)p * PSTRIDE + bofs + (size_t)ch * HWSZ];

    if (p == 1) {
      // xpp[1] = att1 * ( sum_{q!=1} att_q*dp_q + xp1 * sum_{q!=1} att_q )
#pragma unroll
      for (int ch = 0; ch < 10; ++ch)
        xppv[ch] = att[1] * fmaf(sA, xpv[ch], S1[ch]);
    } else {
      // xpp[p] = att1*att_p*(dp1 + xp_p)
      float aa = att[1] * att[p];
#pragma unroll
      for (int ch = 0; ch < 10; ++ch)
        xppv[ch] = aa * (dp1[ch] + xpv[ch]);
    }

#pragma unroll
    for (int ch = 0; ch < 10; ++ch)
      xhpv[ch] = gate[p] * (acc[10 + p * 10 + ch] + ws[OFF_BPROJ + p * 10 + ch]);

#pragma unroll
    for (int ch = 0; ch < 10; ++ch) {
      float u = ws[OFF_BUPD + p * 10 + ch];
      const float* wu = ws + OFF_WUPD + (size_t)(p * 10 + ch) * 30;
#pragma unroll
      for (int j = 0; j < 10; ++j) u = fmaf(wu[j],      xpv[j],  u);
#pragma unroll
      for (int j = 0; j < 10; ++j) u = fmaf(wu[10 + j], xppv[j], u);
#pragma unroll
      for (int j = 0; j < 10; ++j) u = fmaf(wu[20 + j], xhpv[j], u);
      u = fmaxf(u, 0.f);

      size_t oidx = (size_t)p * PSTRIDE + bofs + (size_t)ch * HWSZ;
      out[oidx]                      = xpv[ch] + u;   // xp_out
      out[(size_t)NPER + oidx]       = xppv[ch];      // xpp
      out[(size_t)(2 * NPER) + oidx] = xhpv[ch];      // xhp
    }
  }
}

extern "C" void kernel_launch(void* const* d_in, const int* in_sizes, int n_in,
                              void* d_out, int out_size, void* d_ws, size_t ws_size,
                              hipStream_t stream) {
  const float* p_fea = (const float*)d_in[0];
  const float* xp    = (const float*)d_in[1];
  const float* xh    = (const float*)d_in[2];
  float* ws = (float*)d_ws;

  prep_weights<<<(WS_TOTAL + 255) / 256, 256, 0, stream>>>(
      (const float*)d_in[3],  (const float*)d_in[4],
      (const float*)d_in[5],  (const float*)d_in[6],
      (const float*)d_in[7],  (const float*)d_in[8],
      (const float*)d_in[9],  (const float*)d_in[10],
      (const float*)d_in[11], (const float*)d_in[12],
      (const float*)d_in[13], ws);

  part_graph_main<<<576, 256, 0, stream>>>(
      p_fea, xp, xh, ws, (float*)d_out);
}

// Round 4
// 335.038 us; speedup vs baseline: 2.0116x; 2.0116x over previous
//
#include <hip/hip_runtime.h>

// ---- problem constants ----
#define HWSZ 9216            // 96*96
#define CIN  256
#define NPER 8847360         // P*B*h*HW  (one output tensor, elements)
#define PSTRIDE 1474560      // B*h*HW (part stride)
#define IMG_STRIDE 2359296   // CIN*HW (p_fea batch stride)
#define BHW 92160            // h*HW (batch stride inside a part)

// ---- f32 weight workspace layout (element offsets) ----
#define OFF_WATT  18432
#define OFF_BATT  18492
#define OFF_WDPX  18498
#define OFF_BDP   18598
#define OFF_BPROJ 18608
#define OFF_WGATE 18668
#define OFF_BGATE 18788
#define OFF_WUPD  18794
#define OFF_BUPD  20594
#define WS_TOTAL  20654
// bf16 MFMA A-operand pack: ushort element offset (byte 82944, past f32 region)
#define A_OFF_U16 41472
#define A_ELEMS   20480      // 5 mtiles * 8 ksteps * 64 lanes * 8

typedef __attribute__((ext_vector_type(8))) short short8;
typedef __attribute__((ext_vector_type(4))) float f32x4;
typedef __attribute__((ext_vector_type(4))) float flt4;

static __device__ __forceinline__ unsigned short f2b(float f) {
  union { float f; unsigned int i; } v; v.f = f;
  unsigned int u = v.i;
  return (unsigned short)((u + 0x7fffu + ((u >> 16) & 1u)) >> 16);  // RNE
}
static __device__ __forceinline__ float sigmoidf_(float x) {
  return 1.0f / (1.0f + __expf(-x));
}

// Gather f32 weights into d_ws AND pack the big [70x256] matrix (w_dp_f rows 0..9,
// w_proj rows 10..69) as bf16 MFMA A-fragments:
// A_pack[mtile][kstep][lane][j] = W[m=mtile*16+(lane&15)][k=kstep*32+((lane>>4)&3)*8+j]
__global__ void prep_weights(const float* __restrict__ w_att,
                             const float* __restrict__ b_att,
                             const float* __restrict__ w_dp_f,
                             const float* __restrict__ w_dp_x,
                             const float* __restrict__ b_dp,
                             const float* __restrict__ w_proj,
                             const float* __restrict__ b_proj,
                             const float* __restrict__ w_gate,
                             const float* __restrict__ b_gate,
                             const float* __restrict__ w_upd,
                             const float* __restrict__ b_upd,
                             float* __restrict__ ws)
{
  int i = blockIdx.x * 256 + threadIdx.x;
  if (i < A_ELEMS) {
    int j     = i & 7;
    int lane  = (i >> 3) & 63;
    int kstep = (i >> 9) & 7;
    int mtile = i >> 12;
    int m = mtile * 16 + (lane & 15);
    int k = kstep * 32 + ((lane >> 4) & 3) * 8 + j;
    float wv = (m < 10) ? w_dp_f[m * CIN + k]
             : (m < 70) ? w_proj[(m - 10) * CIN + k] : 0.f;
    ((unsigned short*)ws)[A_OFF_U16 + i] = f2b(wv);
  }
  if (i >= WS_TOTAL || i < OFF_WATT) return;
  float v;
  if      (i < OFF_BATT)  v = w_att [i - OFF_WATT ];
  else if (i < OFF_WDPX)  v = b_att [i - OFF_BATT ];
  else if (i < OFF_BDP)   v = w_dp_x[i - OFF_WDPX ];
  else if (i < OFF_BPROJ) v = b_dp  [i - OFF_BDP  ];
  else if (i < OFF_WGATE) v = b_proj[i - OFF_BPROJ];
  else if (i < OFF_BGATE) v = w_gate[i - OFF_WGATE];
  else if (i < OFF_WUPD)  v = b_gate[i - OFF_BGATE];
  else if (i < OFF_BUPD)  v = w_upd [i - OFF_WUPD ];
  else                    v = b_upd [i - OFF_BUPD ];
  ws[i] = v;
}

// E1: per (pixel,part): att, gate, dp -> LDS
static __device__ __forceinline__ void epilogue1(
    int px, int p, int b, int s0,
    const float* __restrict__ xp, const float* __restrict__ xh,
    const float* __restrict__ ws,
    float* __restrict__ S, float* __restrict__ dpL,
    float* __restrict__ attL, float* __restrict__ gateL)
{
  const size_t base = (size_t)b * BHW + s0 + px;
  const float* xpb = xp + (size_t)p * PSTRIDE + base;
  const float* xhb = xh + (size_t)(p >= 4 ? 1 : 0) * PSTRIDE + base;
  float asum = ws[OFF_BATT + p], gsum = ws[OFF_BGATE + p];
  float xpv[10];
#pragma unroll
  for (int ch = 0; ch < 10; ++ch) {
    float x  = xpb[(size_t)ch * HWSZ];
    float hv = xhb[(size_t)ch * HWSZ];
    xpv[ch] = x;
    asum = fmaf(ws[OFF_WATT + p * 10 + ch], x, asum);
    gsum = fmaf(ws[OFF_WGATE + p * 20 + 10 + ch], x, gsum);
    gsum = fmaf(ws[OFF_WGATE + p * 20 + ch], hv, gsum);
  }
  attL [p * 64 + px] = sigmoidf_(asum);
  gateL[p * 64 + px] = sigmoidf_(gsum);
#pragma unroll
  for (int ch = 0; ch < 10; ++ch) {
    float t = S[ch * 72 + px] + ws[OFF_BDP + ch];
#pragma unroll
    for (int j = 0; j < 10; ++j) t = fmaf(ws[OFF_WDPX + ch * 10 + j], xpv[j], t);
    dpL[(p * 10 + ch) * 64 + px] = fmaxf(t, 0.f);
  }
}

// E2: per (pixel,part): xpp, xhp, update, stores
static __device__ __forceinline__ void epilogue2(
    int px, int p, int b, int s0,
    const float* __restrict__ xp, const float* __restrict__ ws,
    const float* __restrict__ S, const float* __restrict__ dpL,
    const float* __restrict__ attL, const float* __restrict__ gateL,
    float* __restrict__ out)
{
  const size_t base = (size_t)b * BHW + s0 + px;
  const float* xpb = xp + (size_t)p * PSTRIDE + base;
  float xpv[10], xppv[10], xhpv[10];
#pragma unroll
  for (int ch = 0; ch < 10; ++ch) xpv[ch] = xpb[(size_t)ch * HWSZ];
  float att1 = attL[64 + px];
  if (p == 1) {
    float sA = 0.f;
#pragma unroll
    for (int q = 0; q < 6; ++q) if (q != 1) sA += attL[q * 64 + px];
#pragma unroll
    for (int ch = 0; ch < 10; ++ch) {
      float s1 = 0.f;
#pragma unroll
      for (int q = 0; q < 6; ++q)
        if (q != 1) s1 = fmaf(attL[q * 64 + px], dpL[(q * 10 + ch) * 64 + px], s1);
      xppv[ch] = att1 * fmaf(sA, xpv[ch], s1);
    }
  } else {
    float aa = att1 * attL[p * 64 + px];
#pragma unroll
    for (int ch = 0; ch < 10; ++ch)
      xppv[ch] = aa * (dpL[(10 + ch) * 64 + px] + xpv[ch]);
  }
  float g = gateL[p * 64 + px];
#pragma unroll
  for (int ch = 0; ch < 10; ++ch)
    xhpv[ch] = g * (S[(10 + p * 10 + ch) * 72 + px] + ws[OFF_BPROJ + p * 10 + ch]);
  float* o0 = out + (size_t)p * PSTRIDE + base;
#pragma unroll
  for (int ch = 0; ch < 10; ++ch) {
    float u = ws[OFF_BUPD + p * 10 + ch];
    const float* wu = ws + OFF_WUPD + (p * 10 + ch) * 30;
#pragma unroll
    for (int j = 0; j < 10; ++j) u = fmaf(wu[j],      xpv[j],  u);
#pragma unroll
    for (int j = 0; j < 10; ++j) u = fmaf(wu[10 + j], xppv[j], u);
#pragma unroll
    for (int j = 0; j < 10; ++j) u = fmaf(wu[20 + j], xhpv[j], u);
    u = fmaxf(u, 0.f);
    o0[(size_t)ch * HWSZ]                    = xpv[ch] + u;
    o0[(size_t)ch * HWSZ + NPER]             = xppv[ch];
    o0[(size_t)ch * HWSZ + 2 * (size_t)NPER] = xhpv[ch];
  }
}

// grid = 2304 (=147456 px / 64), block = 256 (4 waves). Wave w owns 16 pixels.
__global__ __launch_bounds__(256) void part_graph_main(
    const float* __restrict__ p_fea,
    const float* __restrict__ xp,
    const float* __restrict__ xh,
    const float* __restrict__ ws,
    float* __restrict__ out)
{
  __shared__ __align__(16) char smem[38592];
  unsigned short* Bt = (unsigned short*)smem;          // [64][264] bf16 (staging phase)
  float* S     = (float*)smem;                         // [70][72] f32  (epilogue phase)
  float* dpL   = (float*)(smem + 20160);               // [6][10][64]
  float* attL  = (float*)(smem + 35520);               // [6][64]
  float* gateL = (float*)(smem + 37056);               // [6][64]

  const int tid = threadIdx.x;
  const int b   = blockIdx.x / 144;
  const int s0  = (blockIdx.x % 144) * 64;

  // ---- stage p_fea tile -> LDS bf16, layout Bt[n][k=c] (k-contiguous) ----
  {
    const int lane16 = tid & 15;   // pixel group: n = lane16*4 .. +3
    const int cslot  = tid >> 4;   // channel slot 0..15
    const float* fb = p_fea + (size_t)b * IMG_STRIDE + s0 + lane16 * 4;
    const int nb = lane16 * 4;
#pragma unroll 4
    for (int it = 0; it < 16; ++it) {
      int c = cslot + it * 16;
      flt4 v = *(const flt4*)(fb + (size_t)c * HWSZ);
      Bt[(nb + 0) * 264 + c] = f2b(v.x);
      Bt[(nb + 1) * 264 + c] = f2b(v.y);
      Bt[(nb + 2) * 264 + c] = f2b(v.z);
      Bt[(nb + 3) * 264 + c] = f2b(v.w);
    }
  }
  __syncthreads();

  // ---- B-fragments from LDS (then Bt is dead) ----
  const int wv   = tid >> 6;
  const int lane = tid & 63;
  const int l15  = lane & 15;
  const int quad = lane >> 4;

  short8 bfrag[8];
  {
    const unsigned short* bp = Bt + (wv * 16 + l15) * 264 + quad * 8;
#pragma unroll
    for (int ks = 0; ks < 8; ++ks)
      bfrag[ks] = *(const short8*)(bp + ks * 32);
  }
  __syncthreads();

  // ---- MFMA: D[70x16] = W[70x256] @ F[256x16] per wave ----
  f32x4 acc[5];
  const short8* ap = (const short8*)((const unsigned short*)ws + A_OFF_U16);
#pragma unroll
  for (int mt = 0; mt < 5; ++mt) {
    f32x4 a = {0.f, 0.f, 0.f, 0.f};
#pragma unroll
    for (int ks = 0; ks < 8; ++ks) {
      short8 af = ap[(mt * 8 + ks) * 64 + lane];
      a = __builtin_amdgcn_mfma_f32_16x16x32_bf16(af, bfrag[ks], a, 0, 0, 0);
    }
    acc[mt] = a;
  }

  // ---- transpose acc -> S[m][n] (C/D layout: n=lane&15, m=quad*4+reg) ----
#pragma unroll
  for (int mt = 0; mt < 5; ++mt) {
#pragma unroll
    for (int r = 0; r < 4; ++r) {
      int m = mt * 16 + quad * 4 + r;
      if (m < 70) S[m * 72 + wv * 16 + l15] = acc[mt][r];
    }
  }
  __syncthreads();

  // ---- epilogue phase 1: (px, part) items; part is wave-uniform ----
  { int px = tid & 63, p = tid >> 6;
    epilogue1(px, p, b, s0, xp, xh, ws, S, dpL, attL, gateL); }
  if (tid < 128) {
    int px = tid & 63, p = 4 + (tid >> 6);
    epilogue1(px, p, b, s0, xp, xh, ws, S, dpL, attL, gateL);
  }
  __syncthreads();

  // ---- epilogue phase 2 ----
  { int px = tid & 63, p = tid >> 6;
    epilogue2(px, p, b, s0, xp, ws, S, dpL, attL, gateL, out); }
  if (tid < 128) {
    int px = tid & 63, p = 4 + (tid >> 6);
    epilogue2(px, p, b, s0, xp, ws, S, dpL, attL, gateL, out);
  }
}

extern "C" void kernel_launch(void* const* d_in, const int* in_sizes, int n_in,
                              void* d_out, int out_size, void* d_ws, size_t ws_size,
                              hipStream_t stream) {
  const float* p_fea = (const float*)d_in[0];
  const float* xp    = (const float*)d_in[1];
  const float* xh    = (const float*)d_in[2];
  float* ws = (float*)d_ws;

  prep_weights<<<(WS_TOTAL + 255) / 256, 256, 0, stream>>>(
      (const float*)d_in[3],  (const float*)d_in[4],
      (const float*)d_in[5],  (const float*)d_in[6],
      (const float*)d_in[7],  (const float*)d_in[8],
      (const float*)d_in[9],  (const float*)d_in[10],
      (const float*)d_in[11], (const float*)d_in[12],
      (const float*)d_in[13], ws);

  part_graph_main<<<2304, 256, 0, stream>>>(
      p_fea, xp, xh, ws, (float*)d_out);
}